// Round 13
// baseline (103.830 us; speedup 1.0000x reference)
//
#include <hip/hip_runtime.h>

#define NUM_CLASSES 80
#define N13 507
#define N26 2028
#define N52 8112
#define NANCH (N13 + N26 + N52)   // 10647
#define BATCH 64
#define MAXB 100
#define NB 3720                    // float-bit buckets: (bits>>14) - 0xFC00, scores in (0.5, 79)
#define BOFF 0xFC00u
#define KPT 11                     // ceil(NANCH/1024)
#define TOPK 1024                  // region target size
#define LCAP 4096                  // LDS ring capacity (power of 2)
#define LMASK (LCAP-1)
#define APB 64                     // anchors per 256-thread block (4 lanes/anchor)
#define MW 512                     // matrix window (candidates covered by kill matrix)

typedef unsigned long long u64;

// EXACT division-free IoU>0.5 test: for un>0, RN(inter/un) > 0.5f  <=>
// inter > (0.5 + 2^-25) * un computed exactly in f64 (25-bit x 24-bit mantissa product is exact).
// 0x1.000001p-1 == 0.5 + 2^-25. Round-to-even at the boundary maps to the strict > here.
__device__ __forceinline__ bool sup_cmp(float inter, float un) {
    return (un > 0.f) && ((double)inter > 0x1.000001p-1 * (double)un);
}

__device__ __forceinline__ u64 readlane64(u64 v, int l) {
    unsigned int lo = (unsigned int)__builtin_amdgcn_readlane((int)(v & 0xFFFFFFFFull), l);
    unsigned int hi = (unsigned int)__builtin_amdgcn_readlane((int)(v >> 32), l);
    return ((u64)hi << 32) | (u64)lo;
}

// ---------------- Phase 1: score = p * (float)argmax(classes), 4 lanes per anchor -------------
__global__ __launch_bounds__(256) void score_kernel(
    const float* __restrict__ c13, const float* __restrict__ p13,
    const float* __restrict__ c26, const float* __restrict__ p26,
    const float* __restrict__ c52, const float* __restrict__ p52,
    float* __restrict__ scores)
{
    int a   = blockIdx.x * APB + (threadIdx.x >> 2);
    int sub = threadIdx.x & 3;
    int b   = blockIdx.y;
    if (a >= NANCH) return;
    const float* cbase; const float* pbase;
    if (a < N13)            { cbase = c13 + ((size_t)b*N13 + a) * NUM_CLASSES;           pbase = p13 + (size_t)b*N13 + a; }
    else if (a < N13+N26)   { cbase = c26 + ((size_t)b*N26 + (a-N13)) * NUM_CLASSES;     pbase = p26 + (size_t)b*N26 + (a-N13); }
    else                    { cbase = c52 + ((size_t)b*N52 + (a-N13-N26)) * NUM_CLASSES; pbase = p52 + (size_t)b*N52 + (a-N13-N26); }
    float mx = -1.0f; int mi = 0;
    #pragma unroll
    for (int q = 0; q < 5; ++q) {
        float4 v = *(const float4*)(cbase + q*16 + sub*4);
        int cb = q*16 + sub*4;
        if (v.x > mx) { mx = v.x; mi = cb+0; }   // strict > keeps FIRST max
        if (v.y > mx) { mx = v.y; mi = cb+1; }
        if (v.z > mx) { mx = v.z; mi = cb+2; }
        if (v.w > mx) { mx = v.w; mi = cb+3; }
    }
    #pragma unroll
    for (int off = 1; off < 4; off <<= 1) {
        float ov = __shfl_xor(mx, off);
        int   oi = __shfl_xor(mi, off);
        if (ov > mx || (ov == mx && oi < mi)) { mx = ov; mi = oi; }
    }
    if (sub == 0) scores[(size_t)b*NANCH + a] = pbase[0] * (float)mi;
}

__device__ __forceinline__ float4 load_box(const float* __restrict__ b13,
                                           const float* __restrict__ b26,
                                           const float* __restrict__ b52,
                                           int b, int n)
{
    if (n < N13)          return *(const float4*)(b13 + ((size_t)b*N13 + n)*4);
    else if (n < N13+N26) return *(const float4*)(b26 + ((size_t)b*N26 + (n-N13))*4);
    else                  return *(const float4*)(b52 + ((size_t)b*N52 + (n-N13-N26))*4);
}

// ---------------- Phase 2: top-K counting-sort + matrix-NMS (+ chunked fallback) --------------
// greedy argmax-NMS == scan in (score desc, idx asc) order, accept iff IoU<=0.5 vs all accepted.
__global__ __launch_bounds__(1024) void nms_sort_scan(
    const float* __restrict__ scores,
    const float* __restrict__ b13, const float* __restrict__ b26, const float* __restrict__ b52,
    float* __restrict__ out)
{
    const int b    = blockIdx.x;
    const int tid  = threadIdx.x;
    const int lane = tid & 63;
    const int wid  = tid >> 6;

    __shared__ u64 lst[LCAP];                   // 32 KB sorted candidate ring
    __shared__ unsigned int cnt[NB];            // 14.9 KB
    __shared__ unsigned int wtot[16];
    __shared__ float4 acc4[MAXB];               // accepted canonical boxes
    __shared__ float4 cbb[64];                  // fallback chunk canon boxes
    __shared__ u64 sup_lds[16];
    __shared__ float outrec[MAXB][6];
    __shared__ int accN_s, T_s, L_s;
    // matrix-path storage
    __shared__ float4 obox[MW];                 // original boxes (for clip output)
    __shared__ float  oscor[MW];                // scores
    __shared__ float4 cbx[MW];                  // canonical (y1,x1,y2,x2)
    __shared__ float  car[MW];                  // canonical areas
    __shared__ u64    mat[8][MW + 4];           // kill matrix: word w of row i = mat[w][i] (pad->2-way)
    __shared__ u64    accword[8];

    const float* sc = scores + (size_t)b * NANCH;

    float sreg[KPT];
    #pragma unroll
    for (int k = 0; k < KPT; ++k) {
        int n = tid + (k << 10);
        sreg[k] = (n < NANCH) ? sc[n] : 0.f;
    }

    for (int i = tid; i < NB; i += 1024) cnt[i] = 0u;
    if (tid == 0) accN_s = 0;
    __syncthreads();

    #pragma unroll
    for (int k = 0; k < KPT; ++k) {
        float s = sreg[k];
        if (s > 0.5f) {
            unsigned int bk = (__float_as_uint(s) >> 14) - BOFF;
            if (bk >= NB) bk = NB - 1;
            atomicAdd(&cnt[bk], 1u);
        }
    }
    __syncthreads();

    unsigned int loc[4]; unsigned int s4 = 0u;
    #pragma unroll
    for (int q = 0; q < 4; ++q) {
        int r = tid*4 + q;
        unsigned int v = (r < NB) ? cnt[NB-1-r] : 0u;
        loc[q] = v; s4 += v;
    }
    unsigned int incl = s4;
    #pragma unroll
    for (int off = 1; off < 64; off <<= 1) {
        unsigned int v = __shfl_up(incl, off);
        if (lane >= off) incl += v;
    }
    if (lane == 63) wtot[wid] = incl;
    __syncthreads();
    unsigned int wexcl = 0u, total = 0u;
    #pragma unroll
    for (int w = 0; w < 16; ++w) { unsigned int t = wtot[w]; if (w < wid) wexcl += t; total += t; }
    unsigned int run = wexcl + (incl - s4);
    if (tid == 0) { T_s = 0; L_s = (int)total; }
    __syncthreads();
    #pragma unroll
    for (int q = 0; q < 4; ++q) {
        int r = tid*4 + q;
        if (r < NB) {
            int bk = NB-1-r;
            unsigned int c = loc[q];
            if (run < TOPK && run + c >= TOPK) { T_s = bk; L_s = (int)(run + c); }
            cnt[bk] = run;
            run += c;
        }
    }
    __syncthreads();
    const int total_i = (int)total;
    int Treg = T_s;
    int regionEnd = L_s;

    #pragma unroll
    for (int k = 0; k < KPT; ++k) {
        float s = sreg[k];
        if (s > 0.5f) {
            unsigned int bits = __float_as_uint(s);
            unsigned int bk = (bits >> 14) - BOFF;
            if (bk >= NB) bk = NB - 1;
            if ((int)bk >= Treg) {
                unsigned int pos = atomicAdd(&cnt[bk], 1u);
                lst[pos & LMASK] = ((u64)bits << 32) | (u64)(0xFFFFFFFFu - (unsigned int)(tid + (k<<10)));
            }
        }
    }
    __syncthreads();

    {
        u64 kk[4]; int tt[4];
        #pragma unroll
        for (int i = 0; i < 4; ++i) {
            int p = tid + (i << 10);
            tt[i] = -1; kk[i] = 0ull;
            if (p < regionEnd) {
                u64 key = lst[p & LMASK];
                unsigned int bk = (unsigned int)(key >> 46) - BOFF;
                if (bk >= NB) bk = NB - 1;
                unsigned int st = (bk+1 < NB) ? cnt[bk+1] : 0u;
                unsigned int e  = cnt[bk];
                unsigned int rank = 0u;
                for (unsigned int q = st; q < e; ++q) rank += (lst[q & LMASK] > key) ? 1u : 0u;
                kk[i] = key; tt[i] = (int)(st + rank);
            }
        }
        __syncthreads();
        #pragma unroll
        for (int i = 0; i < 4; ++i) if (tt[i] >= 0) lst[tt[i] & LMASK] = kk[i];
        __syncthreads();
    }

    // ================= MATRIX PATH over first W sorted candidates =================
    int W = total_i; if (W > regionEnd) W = regionEnd; if (W > MW) W = MW;

    // Phase A: load + canonicalize first W candidates into LDS SoA
    if (tid < W) {
        u64 key = lst[tid];
        unsigned int n = 0xFFFFFFFFu - (unsigned int)(key & 0xFFFFFFFFull);
        float4 bbv = load_box(b13, b26, b52, b, (int)n);
        obox[tid]  = bbv;
        oscor[tid] = __uint_as_float((unsigned int)(key >> 32));
        float y1 = fminf(bbv.x, bbv.z), y2 = fmaxf(bbv.x, bbv.z);
        float x1 = fminf(bbv.y, bbv.w), x2 = fmaxf(bbv.y, bbv.w);
        cbx[tid] = make_float4(y1, x1, y2, x2);
        car[tid] = (y2 - y1) * (x2 - x1);       // bit-identical to reference area
    }
    __syncthreads();

    // Phase B: full WxW kill matrix, word-major task mapping (wave-uniform inner address)
    for (int task = tid; task < 8 * MW; task += 1024) {
        int i = task & (MW - 1), w = task >> 9;
        if (i < W) {
            int kbase = w << 6;
            int kend = W - kbase; if (kend > 64) kend = 64;
            float4 ci = cbx[i]; float iar = car[i];
            u64 bits = 0ull;
            for (int k = 0; k < kend; ++k) {
                float4 cj = cbx[kbase + k];
                float jar = car[kbase + k];
                float iy1 = fmaxf(ci.x, cj.x), iy2 = fminf(ci.z, cj.z);
                float ix1 = fmaxf(ci.y, cj.y), ix2 = fminf(ci.w, cj.w);
                float inter = fmaxf(iy2 - iy1, 0.f) * fmaxf(ix2 - ix1, 0.f);
                float un = (iar + jar) - inter;
                if (sup_cmp(inter, un)) bits |= (1ull << k);
            }
            mat[w][i] = bits;
        }
    }
    __syncthreads();

    // Phase C: wave-0 bitmask resolve (1 conflict-free 8-lane ds_read per accept)
    if (wid == 0) {
        u64 remw = 0ull;
        if (lane < 8) {
            int base = lane << 6;
            int nb = W - base;
            remw = (nb >= 64) ? ~0ull : ((nb > 0) ? ((1ull << nb) - 1ull) : 0ull);
        }
        u64 accw = 0ull;
        int acc = 0;
        while (acc < MAXB) {
            u64 bal = __ballot(remw != 0ull);
            if (bal == 0ull) break;
            int fw = (int)__builtin_ctzll(bal);
            u64 w0 = readlane64(remw, fw);
            int j  = (fw << 6) + (int)__builtin_ctzll(w0);
            u64 rowl = 0ull;
            if (lane < 8) rowl = mat[lane][j];   // 8 consecutive u64: conflict-free
            if (lane == (j >> 6)) accw |= (1ull << (j & 63));
            if (lane < 8) remw &= ~rowl;         // row j includes self bit (IoU=1)
            acc++;
        }
        if (lane < 8) accword[lane] = accw;
        if (lane == 0) accN_s = acc;
    }
    __syncthreads();

    // position pass: accepted candidates fill acc4/outrec in ctz (=sorted) order
    int accN = accN_s;
    if (tid < W) {
        int w = tid >> 6, bpos = tid & 63;
        u64 aw = accword[w];
        if ((aw >> bpos) & 1ull) {
            int pos = (int)__popcll(aw & ((1ull << bpos) - 1ull));
            for (int q = 0; q < w; ++q) pos += (int)__popcll(accword[q]);
            float4 ob = obox[tid];
            acc4[pos] = cbx[tid];
            outrec[pos][0] = fminf(fmaxf(ob.x, 0.f), 1.f);
            outrec[pos][1] = fminf(fmaxf(ob.y, 0.f), 1.f);
            outrec[pos][2] = fminf(fmaxf(ob.z, 0.f), 1.f);
            outrec[pos][3] = fminf(fmaxf(ob.w, 0.f), 1.f);
            outrec[pos][4] = oscor[tid];
            outrec[pos][5] = 0.f;
        }
    }
    __syncthreads();

    // ================= FALLBACK: chunked scan from c = W (rare; correctness net) =================
    u64 key = 0ull; float4 bb = make_float4(0.f,0.f,0.f,0.f); float s = 0.f;
    int c = W;
    if (accN < MAXB && c + lane < regionEnd) {
        key = lst[(c + lane) & LMASK];
        unsigned int n = 0xFFFFFFFFu - (unsigned int)(key & 0xFFFFFFFFull);
        s = __uint_as_float((unsigned int)(key >> 32));
        bb = load_box(b13, b26, b52, b, (int)n);
    }

    while (c < total_i && accN < MAXB) {
        while (c + 64 > regionEnd && regionEnd < total_i) {
            int K2 = regionEnd + TOPK;
            if (tid == 0) { T_s = 0; L_s = total_i; }
            __syncthreads();
            for (int bk = tid; bk < Treg; bk += 1024) {
                unsigned int stv = cnt[bk];
                unsigned int ev  = (bk == 0) ? (unsigned int)total_i : cnt[bk-1];
                if (stv < (unsigned int)K2 && ev >= (unsigned int)K2) { T_s = bk; L_s = (int)ev; }
            }
            __syncthreads();
            int T2 = T_s, L2 = L_s;
            #pragma unroll
            for (int k = 0; k < KPT; ++k) {
                float sv = sreg[k];
                if (sv > 0.5f) {
                    unsigned int bits = __float_as_uint(sv);
                    int bk = (int)((bits >> 14) - BOFF);
                    if (bk >= NB) bk = NB - 1;
                    if (bk >= T2 && bk < Treg) {
                        unsigned int pos = atomicAdd(&cnt[bk], 1u);
                        lst[pos & LMASK] = ((u64)bits << 32) | (u64)(0xFFFFFFFFu - (unsigned int)(tid + (k<<10)));
                    }
                }
            }
            __syncthreads();
            {
                u64 kk[4]; int tt[4];
                #pragma unroll
                for (int i = 0; i < 4; ++i) {
                    int p = regionEnd + tid + (i << 10);
                    tt[i] = -1; kk[i] = 0ull;
                    if (p < L2) {
                        u64 k2 = lst[p & LMASK];
                        unsigned int bk = (unsigned int)(k2 >> 46) - BOFF;
                        if (bk >= NB) bk = NB - 1;
                        unsigned int st = (bk+1 < NB) ? cnt[bk+1] : 0u;
                        unsigned int e  = cnt[bk];
                        unsigned int rank = 0u;
                        for (unsigned int q = st; q < e; ++q) rank += (lst[q & LMASK] > k2) ? 1u : 0u;
                        kk[i] = k2; tt[i] = (int)(st + rank);
                    }
                }
                __syncthreads();
                #pragma unroll
                for (int i = 0; i < 4; ++i) if (tt[i] >= 0) lst[tt[i] & LMASK] = kk[i];
                __syncthreads();
            }
            Treg = T2; regionEnd = L2;
            key = 0ull; bb = make_float4(0.f,0.f,0.f,0.f); s = 0.f;
            if (c + lane < regionEnd) {
                key = lst[(c + lane) & LMASK];
                unsigned int n = 0xFFFFFFFFu - (unsigned int)(key & 0xFFFFFFFFull);
                s = __uint_as_float((unsigned int)(key >> 32));
                bb = load_box(b13, b26, b52, b, (int)n);
            }
        }

        int m = regionEnd - c; if (m > 64) m = 64;
        float oy1 = bb.x, ox1 = bb.y, oy2 = bb.z, ox2 = bb.w, cs = s;
        float y1 = fminf(oy1, oy2), y2 = fmaxf(oy1, oy2);
        float x1 = fminf(ox1, ox2), x2 = fmaxf(ox1, ox2);
        float ar = (y2-y1)*(x2-x1);

        int nc = c + 64;
        if (nc + lane < regionEnd) {
            key = lst[(nc + lane) & LMASK];
            unsigned int n = 0xFFFFFFFFu - (unsigned int)(key & 0xFFFFFFFFull);
            s = __uint_as_float((unsigned int)(key >> 32));
            bb = load_box(b13, b26, b52, b, (int)n);
        } else { s = 0.f; bb = make_float4(0.f,0.f,0.f,0.f); }

        bool supp = (lane >= m);
        #pragma unroll 2
        for (int j = wid; j < accN; j += 16) {
            float4 aj = acc4[j];
            float jar = (aj.z - aj.x) * (aj.w - aj.y);
            float iy1=fmaxf(y1,aj.x), iy2=fminf(y2,aj.z);
            float ix1=fmaxf(x1,aj.y), ix2=fminf(x2,aj.w);
            float inter=fmaxf(iy2-iy1,0.f)*fmaxf(ix2-ix1,0.f);
            float un=(ar+jar)-inter;
            supp |= sup_cmp(inter, un);
        }
        u64 bal = __ballot(supp);
        if (lane == 0) sup_lds[wid] = bal;

        u64 myrow = 0ull;
        if (wid == 0) {
            cbb[lane] = make_float4(y1, x1, y2, x2);
            #pragma unroll 4
            for (int k = 0; k < m; ++k) {
                float4 ck = cbb[k];
                float kar = (ck.z - ck.x) * (ck.w - ck.y);
                float iy1=fmaxf(y1,ck.x), iy2=fminf(y2,ck.z);
                float ix1=fmaxf(x1,ck.y), ix2=fminf(x2,ck.w);
                float inter=fmaxf(iy2-iy1,0.f)*fmaxf(ix2-ix1,0.f);
                float un=(ar+kar)-inter;
                if (sup_cmp(inter, un)) myrow |= (1ull << k);
            }
        }
        __syncthreads();

        if (wid == 0) {
            u64 B = 0ull;
            #pragma unroll
            for (int w = 0; w < 16; ++w) B |= sup_lds[w];
            u64 valid_m = (m >= 64) ? ~0ull : ((1ull << m) - 1ull);
            u64 rem = (~B) & valid_m;
            u64 accmask = 0ull;
            const int start = accN;
            while (rem && accN < MAXB) {
                int j = __builtin_ctzll(rem);
                u64 rowj = readlane64(myrow, j);
                accmask |= (1ull << j);
                rem &= ~rowj;
                rem &= ~(1ull << j);
                accN++;
            }
            if (accmask & (1ull << lane)) {
                int pos = start + (int)__popcll(accmask & ((1ull << lane) - 1ull));
                acc4[pos] = make_float4(y1, x1, y2, x2);
                outrec[pos][0]=fminf(fmaxf(oy1,0.f),1.f);
                outrec[pos][1]=fminf(fmaxf(ox1,0.f),1.f);
                outrec[pos][2]=fminf(fmaxf(oy2,0.f),1.f);
                outrec[pos][3]=fminf(fmaxf(ox2,0.f),1.f);
                outrec[pos][4]=cs;
                outrec[pos][5]=0.f;
            }
            if (lane == 0) accN_s = accN;
        }
        __syncthreads();
        accN = accN_s;
        c += 64;
    }

    // ---- block-wide output write ----
    const int accNf = accN_s;
    float* outp = out + (size_t)b * (MAXB*6);
    for (int i = tid; i < MAXB*6; i += 1024) {
        int t = i / 6;
        outp[i] = (t < accNf) ? outrec[t][i % 6] : 0.f;
    }
    if (tid == 0) out[(size_t)BATCH*(MAXB*6) + b] = (float)accNf;
}

extern "C" void kernel_launch(void* const* d_in, const int* in_sizes, int n_in,
                              void* d_out, int out_size, void* d_ws, size_t ws_size,
                              hipStream_t stream)
{
    const float* bbox13 = (const float*)d_in[0];
    const float* p13    = (const float*)d_in[1];
    const float* c13    = (const float*)d_in[2];
    const float* bbox26 = (const float*)d_in[3];
    const float* p26    = (const float*)d_in[4];
    const float* c26    = (const float*)d_in[5];
    const float* bbox52 = (const float*)d_in[6];
    const float* p52    = (const float*)d_in[7];
    const float* c52    = (const float*)d_in[8];
    float* out    = (float*)d_out;
    float* scores = (float*)d_ws;   // 64*10647*4 = 2.7 MB

    dim3 g1((NANCH + APB - 1)/APB, BATCH);
    score_kernel<<<g1, 256, 0, stream>>>(c13, p13, c26, p26, c52, p52, scores);
    nms_sort_scan<<<BATCH, 1024, 0, stream>>>(scores, bbox13, bbox26, bbox52, out);
}

// Round 14
// 57.267 us; speedup vs baseline: 1.8131x; 1.8131x over previous
//
#include <hip/hip_runtime.h>

#define NUM_CLASSES 80
#define N13 507
#define N26 2028
#define N52 8112
#define NANCH (N13 + N26 + N52)   // 10647
#define BATCH 64
#define MAXB 100
#define NB 3720                    // float-bit buckets: (bits>>14) - 0xFC00, scores in (0.5, 79)
#define BOFF 0xFC00u
#define KPT 11                     // ceil(NANCH/1024)
#define TOPK 1024                  // region target size
#define LCAP 4096                  // LDS ring capacity (power of 2)
#define LMASK (LCAP-1)
#define APB 64                     // anchors per 256-thread block (4 lanes/anchor)

typedef unsigned long long u64;

// EXACT division-free IoU>0.5 test (validated on-data in R13): for un>0,
// RN(inter/un) > 0.5f  <=>  (double)inter > (0.5 + 2^-25)*(double)un  (product exact in f64).
__device__ __forceinline__ bool sup_cmp(float inter, float un) {
    return (un > 0.f) && ((double)inter > 0x1.000001p-1 * (double)un);
}

__device__ __forceinline__ u64 readlane64(u64 v, int l) {
    unsigned int lo = (unsigned int)__builtin_amdgcn_readlane((int)(v & 0xFFFFFFFFull), l);
    unsigned int hi = (unsigned int)__builtin_amdgcn_readlane((int)(v >> 32), l);
    return ((u64)hi << 32) | (u64)lo;
}

// ---------------- Phase 1: score = p * (float)argmax(classes), 4 lanes per anchor -------------
__global__ __launch_bounds__(256) void score_kernel(
    const float* __restrict__ c13, const float* __restrict__ p13,
    const float* __restrict__ c26, const float* __restrict__ p26,
    const float* __restrict__ c52, const float* __restrict__ p52,
    float* __restrict__ scores)
{
    int a   = blockIdx.x * APB + (threadIdx.x >> 2);
    int sub = threadIdx.x & 3;
    int b   = blockIdx.y;
    if (a >= NANCH) return;
    const float* cbase; const float* pbase;
    if (a < N13)            { cbase = c13 + ((size_t)b*N13 + a) * NUM_CLASSES;           pbase = p13 + (size_t)b*N13 + a; }
    else if (a < N13+N26)   { cbase = c26 + ((size_t)b*N26 + (a-N13)) * NUM_CLASSES;     pbase = p26 + (size_t)b*N26 + (a-N13); }
    else                    { cbase = c52 + ((size_t)b*N52 + (a-N13-N26)) * NUM_CLASSES; pbase = p52 + (size_t)b*N52 + (a-N13-N26); }
    float mx = -1.0f; int mi = 0;
    #pragma unroll
    for (int q = 0; q < 5; ++q) {
        float4 v = *(const float4*)(cbase + q*16 + sub*4);
        int cb = q*16 + sub*4;
        if (v.x > mx) { mx = v.x; mi = cb+0; }   // strict > keeps FIRST max
        if (v.y > mx) { mx = v.y; mi = cb+1; }
        if (v.z > mx) { mx = v.z; mi = cb+2; }
        if (v.w > mx) { mx = v.w; mi = cb+3; }
    }
    #pragma unroll
    for (int off = 1; off < 4; off <<= 1) {
        float ov = __shfl_xor(mx, off);
        int   oi = __shfl_xor(mi, off);
        if (ov > mx || (ov == mx && oi < mi)) { mx = ov; mi = oi; }
    }
    if (sub == 0) scores[(size_t)b*NANCH + a] = pbase[0] * (float)mi;
}

__device__ __forceinline__ float4 load_box(const float* __restrict__ b13,
                                           const float* __restrict__ b26,
                                           const float* __restrict__ b52,
                                           int b, int n)
{
    if (n < N13)          return *(const float4*)(b13 + ((size_t)b*N13 + n)*4);
    else if (n < N13+N26) return *(const float4*)(b26 + ((size_t)b*N26 + (n-N13))*4);
    else                  return *(const float4*)(b52 + ((size_t)b*N52 + (n-N13-N26))*4);
}

// ---------------- Phase 2: top-K counting-sort + wave-parallel scan NMS ----------------
// greedy argmax-NMS == scan in (score desc, idx asc) order, accept iff IoU<=0.5 vs all accepted.
__global__ __launch_bounds__(1024) void nms_sort_scan(
    const float* __restrict__ scores,
    const float* __restrict__ b13, const float* __restrict__ b26, const float* __restrict__ b52,
    float* __restrict__ out)
{
    const int b    = blockIdx.x;
    const int tid  = threadIdx.x;
    const int lane = tid & 63;
    const int wid  = tid >> 6;

    __shared__ u64 lst[LCAP];                   // 32 KB ring of sorted candidates
    __shared__ unsigned int cnt[NB];            // 14.9 KB
    __shared__ unsigned int wtot[16];
    __shared__ float4 acc4[MAXB];               // accepted canonical boxes (y1,x1,y2,x2)
    __shared__ u64 kmat[64];                    // per-chunk kill rows (row r = victims of r)
    __shared__ u64 sup_lds[16];
    __shared__ float outrec[MAXB][6];
    __shared__ int accN_s, T_s, L_s;

    const float* sc = scores + (size_t)b * NANCH;

    float sreg[KPT];
    #pragma unroll
    for (int k = 0; k < KPT; ++k) {
        int n = tid + (k << 10);
        sreg[k] = (n < NANCH) ? sc[n] : 0.f;
    }

    for (int i = tid; i < NB; i += 1024) cnt[i] = 0u;
    if (tid == 0) accN_s = 0;
    __syncthreads();

    #pragma unroll
    for (int k = 0; k < KPT; ++k) {
        float s = sreg[k];
        if (s > 0.5f) {
            unsigned int bk = (__float_as_uint(s) >> 14) - BOFF;
            if (bk >= NB) bk = NB - 1;
            atomicAdd(&cnt[bk], 1u);
        }
    }
    __syncthreads();

    unsigned int loc[4]; unsigned int s4 = 0u;
    #pragma unroll
    for (int q = 0; q < 4; ++q) {
        int r = tid*4 + q;
        unsigned int v = (r < NB) ? cnt[NB-1-r] : 0u;
        loc[q] = v; s4 += v;
    }
    unsigned int incl = s4;
    #pragma unroll
    for (int off = 1; off < 64; off <<= 1) {
        unsigned int v = __shfl_up(incl, off);
        if (lane >= off) incl += v;
    }
    if (lane == 63) wtot[wid] = incl;
    __syncthreads();
    unsigned int wexcl = 0u, total = 0u;
    #pragma unroll
    for (int w = 0; w < 16; ++w) { unsigned int t = wtot[w]; if (w < wid) wexcl += t; total += t; }
    unsigned int run = wexcl + (incl - s4);
    if (tid == 0) { T_s = 0; L_s = (int)total; }
    __syncthreads();
    #pragma unroll
    for (int q = 0; q < 4; ++q) {
        int r = tid*4 + q;
        if (r < NB) {
            int bk = NB-1-r;
            unsigned int c = loc[q];
            if (run < TOPK && run + c >= TOPK) { T_s = bk; L_s = (int)(run + c); }
            cnt[bk] = run;
            run += c;
        }
    }
    __syncthreads();
    const int total_i = (int)total;
    int Treg = T_s;
    int regionEnd = L_s;

    #pragma unroll
    for (int k = 0; k < KPT; ++k) {
        float s = sreg[k];
        if (s > 0.5f) {
            unsigned int bits = __float_as_uint(s);
            unsigned int bk = (bits >> 14) - BOFF;
            if (bk >= NB) bk = NB - 1;
            if ((int)bk >= Treg) {
                unsigned int pos = atomicAdd(&cnt[bk], 1u);
                lst[pos & LMASK] = ((u64)bits << 32) | (u64)(0xFFFFFFFFu - (unsigned int)(tid + (k<<10)));
            }
        }
    }
    __syncthreads();

    {
        u64 kk[4]; int tt[4];
        #pragma unroll
        for (int i = 0; i < 4; ++i) {
            int p = tid + (i << 10);
            tt[i] = -1; kk[i] = 0ull;
            if (p < regionEnd) {
                u64 key = lst[p & LMASK];
                unsigned int bk = (unsigned int)(key >> 46) - BOFF;
                if (bk >= NB) bk = NB - 1;
                unsigned int st = (bk+1 < NB) ? cnt[bk+1] : 0u;
                unsigned int e  = cnt[bk];
                unsigned int rank = 0u;
                for (unsigned int q = st; q < e; ++q) rank += (lst[q & LMASK] > key) ? 1u : 0u;
                kk[i] = key; tt[i] = (int)(st + rank);
            }
        }
        __syncthreads();
        #pragma unroll
        for (int i = 0; i < 4; ++i) if (tt[i] >= 0) lst[tt[i] & LMASK] = kk[i];
        __syncthreads();
    }

    // ---- wave-parallel chunked scan ----
    int accN = 0;
    u64 key = 0ull; float4 bb = make_float4(0.f,0.f,0.f,0.f); float s = 0.f;
    if (lane < regionEnd) {
        key = lst[lane];
        unsigned int n = 0xFFFFFFFFu - (unsigned int)(key & 0xFFFFFFFFull);
        s = __uint_as_float((unsigned int)(key >> 32));
        bb = load_box(b13, b26, b52, b, (int)n);
    }

    int c = 0;
    while (c < total_i && accN < MAXB) {
        // ---- region extension (fallback; never taken for bench data) ----
        while (c + 64 > regionEnd && regionEnd < total_i) {
            int K2 = regionEnd + TOPK;
            if (tid == 0) { T_s = 0; L_s = total_i; }
            __syncthreads();
            for (int bk = tid; bk < Treg; bk += 1024) {
                unsigned int stv = cnt[bk];
                unsigned int ev  = (bk == 0) ? (unsigned int)total_i : cnt[bk-1];
                if (stv < (unsigned int)K2 && ev >= (unsigned int)K2) { T_s = bk; L_s = (int)ev; }
            }
            __syncthreads();
            int T2 = T_s, L2 = L_s;
            #pragma unroll
            for (int k = 0; k < KPT; ++k) {
                float sv = sreg[k];
                if (sv > 0.5f) {
                    unsigned int bits = __float_as_uint(sv);
                    int bk = (int)((bits >> 14) - BOFF);
                    if (bk >= NB) bk = NB - 1;
                    if (bk >= T2 && bk < Treg) {
                        unsigned int pos = atomicAdd(&cnt[bk], 1u);
                        lst[pos & LMASK] = ((u64)bits << 32) | (u64)(0xFFFFFFFFu - (unsigned int)(tid + (k<<10)));
                    }
                }
            }
            __syncthreads();
            {
                u64 kk[4]; int tt[4];
                #pragma unroll
                for (int i = 0; i < 4; ++i) {
                    int p = regionEnd + tid + (i << 10);
                    tt[i] = -1; kk[i] = 0ull;
                    if (p < L2) {
                        u64 k2 = lst[p & LMASK];
                        unsigned int bk = (unsigned int)(k2 >> 46) - BOFF;
                        if (bk >= NB) bk = NB - 1;
                        unsigned int st = (bk+1 < NB) ? cnt[bk+1] : 0u;
                        unsigned int e  = cnt[bk];
                        unsigned int rank = 0u;
                        for (unsigned int q = st; q < e; ++q) rank += (lst[q & LMASK] > k2) ? 1u : 0u;
                        kk[i] = k2; tt[i] = (int)(st + rank);
                    }
                }
                __syncthreads();
                #pragma unroll
                for (int i = 0; i < 4; ++i) if (tt[i] >= 0) lst[tt[i] & LMASK] = kk[i];
                __syncthreads();
            }
            Treg = T2; regionEnd = L2;
            key = 0ull; bb = make_float4(0.f,0.f,0.f,0.f); s = 0.f;
            if (c + lane < regionEnd) {
                key = lst[(c + lane) & LMASK];
                unsigned int n = 0xFFFFFFFFu - (unsigned int)(key & 0xFFFFFFFFull);
                s = __uint_as_float((unsigned int)(key >> 32));
                bb = load_box(b13, b26, b52, b, (int)n);
            }
        }

        int m = regionEnd - c; if (m > 64) m = 64;
        float oy1 = bb.x, ox1 = bb.y, oy2 = bb.z, ox2 = bb.w, cs = s;
        float y1 = fminf(oy1, oy2), y2 = fmaxf(oy1, oy2);
        float x1 = fminf(ox1, ox2), x2 = fmaxf(ox1, ox2);
        float ar = (y2-y1)*(x2-x1);

        // prefetch next chunk
        int nc = c + 64;
        if (nc + lane < regionEnd) {
            key = lst[(nc + lane) & LMASK];
            unsigned int n = 0xFFFFFFFFu - (unsigned int)(key & 0xFFFFFFFFull);
            s = __uint_as_float((unsigned int)(key >> 32));
            bb = load_box(b13, b26, b52, b, (int)n);
        } else { s = 0.f; bb = make_float4(0.f,0.f,0.f,0.f); }

        // --- acc-check: wave w tests accepted slice {w, w+16, ...}; pipelined LDS reads ---
        bool supp = (lane >= m);
        #pragma unroll 2
        for (int j = wid; j < accN; j += 16) {
            float4 aj = acc4[j];                 // broadcast read, conflict-free
            float jar = (aj.z - aj.x) * (aj.w - aj.y);   // bit-identical to ref's area
            float iy1=fmaxf(y1,aj.x), iy2=fminf(y2,aj.z);
            float ix1=fmaxf(x1,aj.y), ix2=fminf(x2,aj.w);
            float inter=fmaxf(iy2-iy1,0.f)*fmaxf(ix2-ix1,0.f);
            float un=(ar+jar)-inter;
            supp |= sup_cmp(inter, un);
        }
        u64 bal = __ballot(supp);
        if (lane == 0) sup_lds[wid] = bal;

        // --- distributed kill-row build: wave w builds rows {w, w+16, w+32, w+48} via shfl ---
        // IoU symmetric + bitwise-commutative ops => row(r) == column(r); R12/R13 validated.
        #pragma unroll
        for (int q = 0; q < 4; ++q) {
            int rr = wid + (q << 4);
            float ry1=__shfl(y1,rr), rx1=__shfl(x1,rr), ry2=__shfl(y2,rr), rx2=__shfl(x2,rr);
            float rar=__shfl(ar,rr);
            float iy1=fmaxf(y1,ry1), iy2=fminf(y2,ry2);
            float ix1=fmaxf(x1,rx1), ix2=fminf(x2,rx2);
            float inter=fmaxf(iy2-iy1,0.f)*fmaxf(ix2-ix1,0.f);
            float un=(ar+rar)-inter;
            u64 kb = __ballot(sup_cmp(inter, un));
            if (lane == 0) kmat[rr] = kb;
        }
        __syncthreads();                         // sup_lds + kmat visible

        // --- wave0: one-shot row fetch + pure readlane resolve ---
        if (wid == 0) {
            u64 myrow = kmat[lane];              // single ds_read_b64, ~4-way (free-ish)
            u64 B = 0ull;
            #pragma unroll
            for (int w = 0; w < 16; ++w) B |= sup_lds[w];
            u64 valid_m = (m >= 64) ? ~0ull : ((1ull << m) - 1ull);
            u64 rem = (~B) & valid_m;
            u64 accmask = 0ull;
            const int start = accN;
            while (rem && accN < MAXB) {
                int j = __builtin_ctzll(rem);
                u64 rowj = readlane64(myrow, j); // victims of j (== killers of j by symmetry)
                accmask |= (1ull << j);
                rem &= ~rowj;
                rem &= ~(1ull << j);
                accN++;
            }
            if (accmask & (1ull << lane)) {
                int pos = start + (int)__popcll(accmask & ((1ull << lane) - 1ull));
                acc4[pos] = make_float4(y1, x1, y2, x2);
                outrec[pos][0]=fminf(fmaxf(oy1,0.f),1.f);
                outrec[pos][1]=fminf(fmaxf(ox1,0.f),1.f);
                outrec[pos][2]=fminf(fmaxf(oy2,0.f),1.f);
                outrec[pos][3]=fminf(fmaxf(ox2,0.f),1.f);
                outrec[pos][4]=cs;
                outrec[pos][5]=0.f;
            }
            if (lane == 0) accN_s = accN;
        }
        __syncthreads();
        accN = accN_s;
        c += 64;
    }

    // ---- block-wide output write ----
    const int accNf = accN_s;
    float* outp = out + (size_t)b * (MAXB*6);
    for (int i = tid; i < MAXB*6; i += 1024) {
        int t = i / 6;
        outp[i] = (t < accNf) ? outrec[t][i % 6] : 0.f;
    }
    if (tid == 0) out[(size_t)BATCH*(MAXB*6) + b] = (float)accNf;
}

extern "C" void kernel_launch(void* const* d_in, const int* in_sizes, int n_in,
                              void* d_out, int out_size, void* d_ws, size_t ws_size,
                              hipStream_t stream)
{
    const float* bbox13 = (const float*)d_in[0];
    const float* p13    = (const float*)d_in[1];
    const float* c13    = (const float*)d_in[2];
    const float* bbox26 = (const float*)d_in[3];
    const float* p26    = (const float*)d_in[4];
    const float* c26    = (const float*)d_in[5];
    const float* bbox52 = (const float*)d_in[6];
    const float* p52    = (const float*)d_in[7];
    const float* c52    = (const float*)d_in[8];
    float* out    = (float*)d_out;
    float* scores = (float*)d_ws;   // 64*10647*4 = 2.7 MB

    dim3 g1((NANCH + APB - 1)/APB, BATCH);
    score_kernel<<<g1, 256, 0, stream>>>(c13, p13, c26, p26, c52, p52, scores);
    nms_sort_scan<<<BATCH, 1024, 0, stream>>>(scores, bbox13, bbox26, bbox52, out);
}